// Round 1
// baseline (51.580 us; speedup 1.0000x reference)
//
#include <hip/hip_runtime.h>
#include <math.h>

// Problem geometry (fixed by reference):
//   in0: venueid2coor  [N_POI, 2]   f32  (UNUSED by the output)
//   in1: inputs_wekn   [B, S]       int32 indices into [0, N_POI)
//   in2: poi_freq      [N_POI, 168] f32
//   out: softmax(poi_freq, axis=1)[idx]  -> [B, S, 168] f32
#define NBINS 168

// One 64-lane wave per output row. Row = 168 f32 = 84 float2 (672 B,
// 16B-aligned since 672 % 16 == 0). Lane l holds float2 pairs:
//   a = row2[l]        (elements 2l, 2l+1;     l in [0,64) -> elems 0..127)
//   b = row2[64 + l]   (elements 128+2l, ...;  only l < 20 valid -> 128..167)
__global__ __launch_bounds__(256) void attn_softmax_gather(
    const float* __restrict__ freq,   // [N_POI, NBINS]
    const int*   __restrict__ idx,    // [R]
    float*       __restrict__ out,    // [R, NBINS]
    int R)
{
    const int lane          = threadIdx.x & 63;
    const int waveInBlock   = threadIdx.x >> 6;
    const int wavesPerBlock = blockDim.x >> 6;
    const int nWaves        = gridDim.x * wavesPerBlock;
    int wave = blockIdx.x * wavesPerBlock + waveInBlock;

    const bool tail = (lane < (NBINS - 128) / 2);   // lane < 20

    for (int row = wave; row < R; row += nWaves) {
        const int p = idx[row];                      // wave-uniform broadcast load
        const float2* src2 = reinterpret_cast<const float2*>(
            freq + (size_t)p * NBINS);

        float2 a = src2[lane];
        float2 b = tail ? src2[64 + lane]
                        : make_float2(-INFINITY, -INFINITY);

        // --- wave max ---
        float m = fmaxf(fmaxf(a.x, a.y), fmaxf(b.x, b.y));
        #pragma unroll
        for (int off = 32; off > 0; off >>= 1)
            m = fmaxf(m, __shfl_xor(m, off, 64));

        // --- exp + wave sum ---
        const float LOG2E = 1.44269504088896f;
        float e0 = exp2f((a.x - m) * LOG2E);
        float e1 = exp2f((a.y - m) * LOG2E);
        float e2 = tail ? exp2f((b.x - m) * LOG2E) : 0.0f;
        float e3 = tail ? exp2f((b.y - m) * LOG2E) : 0.0f;
        float s = (e0 + e1) + (e2 + e3);
        #pragma unroll
        for (int off = 32; off > 0; off >>= 1)
            s += __shfl_xor(s, off, 64);

        const float inv = 1.0f / s;

        float2* dst2 = reinterpret_cast<float2*>(out + (size_t)row * NBINS);
        dst2[lane] = make_float2(e0 * inv, e1 * inv);
        if (tail)
            dst2[64 + lane] = make_float2(e2 * inv, e3 * inv);
    }
}

extern "C" void kernel_launch(void* const* d_in, const int* in_sizes, int n_in,
                              void* d_out, int out_size, void* d_ws, size_t ws_size,
                              hipStream_t stream) {
    (void)n_in; (void)d_ws; (void)ws_size;
    const int*   idx  = (const int*)  d_in[1];   // inputs_wekn [B*S]
    const float* freq = (const float*)d_in[2];   // poi_freq    [N_POI*168]
    float* out = (float*)d_out;

    const int R = in_sizes[1];                   // B*S = 204800 rows

    // Memory-bound: cap grid and grid-stride (G11). 2048 blocks x 4 waves
    // = 8192 waves; each handles ~25 rows.
    const int block = 256;
    const int wavesPerBlock = block / 64;
    int blocks = (R + wavesPerBlock - 1) / wavesPerBlock;
    if (blocks > 2048) blocks = 2048;

    attn_softmax_gather<<<blocks, block, 0, stream>>>(freq, idx, out, R);
}